// Round 5
// baseline (97.903 us; speedup 1.0000x reference)
//
#include <hip/hip_runtime.h>
#include <math.h>

#define REFRACTORY 0.33f
#define FILT_WORDS 8192      // 32 KB LDS coarse filter: 262144 bits
#define QCAP 1000            // per-block LDS queue entries (8 KB as int2)
#define QMAX_DEFAULT (4*1024*1024)

// ws layout:
//   [0,4)    flag (rec_mask byte-mode)
//   [4,8)    qcount
//   [256, 256+4*N)  acc
//   then qbuf (int2 candidate entries)
#define WS_ACC_OFF 256

// ---------------------------------------------------------------------------
// Kernel 1 (setup): block 0 detects rec_mask storage mode + zeroes qcount;
// blocks 1.. initialize acc at output-neuron positions.
// (int32 mode: dwords are 0/1; packed bool bytes: dword view gives >1.)
// ---------------------------------------------------------------------------
__global__ void setup(const unsigned int* __restrict__ rm, int nwords,
                      int* __restrict__ flag, int* __restrict__ qcount,
                      const int* __restrict__ out_ids,
                      const float* __restrict__ state,
                      const float* __restrict__ biases,
                      float* __restrict__ acc, int nout) {
    if (blockIdx.x == 0) {
        __shared__ int s;
        if (threadIdx.x == 0) { s = 0; *qcount = 0; }
        __syncthreads();
        int found = 0;
        for (int i = threadIdx.x; i < nwords; i += blockDim.x)
            if (rm[i] > 1u) found = 1;
        if (found) atomicOr(&s, 1);
        __syncthreads();
        if (threadIdx.x == 0) *flag = s;
    } else {
        int i = (blockIdx.x - 1) * blockDim.x + threadIdx.x;
        if (i < nout) {
            int n = out_ids[i];
            acc[n] = REFRACTORY * state[n] + biases[n];
        }
    }
}

// ---------------------------------------------------------------------------
// Full edge processing. False positives are harmless: acc is only read at
// out_ids positions, so adds landing elsewhere are never observed.
// ---------------------------------------------------------------------------
__device__ __forceinline__ void process_edge(
    int d, int e,
    const float* __restrict__ w, const int* __restrict__ src,
    const unsigned char* __restrict__ rmb, const int* __restrict__ input_idx,
    const float* __restrict__ state, const float* __restrict__ inp,
    float* __restrict__ acc, int bytemode) {
    int m = bytemode ? (int)rmb[e] : ((const int*)rmb)[e];
    float v = m ? REFRACTORY * state[src[e]] : inp[input_idx[e]];
    unsafeAtomicAdd(&acc[d], w[e] * v);
}

// ---------------------------------------------------------------------------
// Kernel 2 (phase A): build LDS coarse filter from out_ids, stream dst,
// enqueue (e, d) candidate pairs into a block-local LDS queue, flush once.
// No scattered global loads in the streaming loop.
// ---------------------------------------------------------------------------
__global__ void __launch_bounds__(256, 4)
edge_compact(const int* __restrict__ dst,
             const int* __restrict__ out_ids, int nout,
             int E, int shift,
             int2* __restrict__ qbuf, int* __restrict__ qcount, int qmax,
             const float* __restrict__ w, const int* __restrict__ src,
             const unsigned char* __restrict__ rmb,
             const int* __restrict__ input_idx,
             const float* __restrict__ state, const float* __restrict__ inp,
             float* __restrict__ acc,
             const int* __restrict__ flag) {
    __shared__ unsigned int filt[FILT_WORDS];
    __shared__ int2 lq[QCAP];
    __shared__ int lcnt, lbase;
    // zero + build coarse filter from out_ids (L2-hot broadcast read)
    {
        uint4* f4 = (uint4*)filt;
        uint4 z = make_uint4(0, 0, 0, 0);
        for (int i = threadIdx.x; i < FILT_WORDS / 4; i += blockDim.x)
            f4[i] = z;
    }
    if (threadIdx.x == 0) lcnt = 0;
    __syncthreads();
    for (int i = threadIdx.x; i < nout; i += blockDim.x) {
        unsigned g = ((unsigned)out_ids[i]) >> shift;
        atomicOr(&filt[g >> 5], 1u << (g & 31));
    }
    __syncthreads();

    const int bytemode = *flag;
    const int sh5 = shift + 5;
    int gtid = blockIdx.x * blockDim.x + threadIdx.x;
    int gstride = gridDim.x * blockDim.x;
    int nq = E >> 2;
    const int4* d4p = (const int4*)dst;

#define SLOT(dv, ev, valid)                                                    \
    {                                                                          \
        unsigned dd = (unsigned)(dv);                                          \
        bool c = (valid) && ((filt[dd >> sh5] >> ((dd >> shift) & 31)) & 1u);  \
        if (c) {                                                               \
            int off = atomicAdd(&lcnt, 1);                                     \
            if (off < QCAP) lq[off] = make_int2((ev), (int)dd);                \
            else process_edge((int)dd, (ev), w, src, rmb, input_idx,           \
                              state, inp, acc, bytemode);                      \
        }                                                                      \
    }

    for (int t = gtid; t < nq; t += 2 * gstride) {
        int4 A = d4p[t];
        int t2 = t + gstride;
        bool has2 = (t2 < nq);
        int4 B = has2 ? d4p[t2] : make_int4(0, 0, 0, 0);
        int ea = t << 2;
        SLOT(A.x, ea + 0, true);
        SLOT(A.y, ea + 1, true);
        SLOT(A.z, ea + 2, true);
        SLOT(A.w, ea + 3, true);
        int eb = t2 << 2;
        SLOT(B.x, eb + 0, has2);
        SLOT(B.y, eb + 1, has2);
        SLOT(B.z, eb + 2, has2);
        SLOT(B.w, eb + 3, has2);
    }
#undef SLOT

    // tail edges (E not divisible by 4): process inline (false-pos-free path)
    int rem = E - nq * 4;
    if (gtid < rem) {
        int e = nq * 4 + gtid;
        int d = dst[e];
        process_edge(d, e, w, src, rmb, input_idx, state, inp, acc, bytemode);
    }

    // block flush
    __syncthreads();
    int n = lcnt < QCAP ? lcnt : QCAP;
    if (threadIdx.x == 0) lbase = atomicAdd(qcount, n);
    __syncthreads();
    int base = lbase;
    for (int i = threadIdx.x; i < n; i += blockDim.x) {
        int gi = base + i;
        if (gi < qmax) qbuf[gi] = lq[i];
        else {  // global queue overflow (rare/never): process inline
            int2 c = lq[i];
            process_edge(c.y, c.x, w, src, rmb, input_idx, state, inp, acc, bytemode);
        }
    }
}

// ---------------------------------------------------------------------------
// Kernel 3 (phase B): process compacted (e, d) candidates; one lane per edge.
// All scattered loads are lane-independent -> latency fully hidden.
// ---------------------------------------------------------------------------
__global__ void __launch_bounds__(256)
process_candidates(const int2* __restrict__ qbuf, const int* __restrict__ qcount,
                   int qmax,
                   const float* __restrict__ w, const int* __restrict__ src,
                   const unsigned char* __restrict__ rmb,
                   const int* __restrict__ input_idx,
                   const float* __restrict__ state, const float* __restrict__ inp,
                   float* __restrict__ acc,
                   const int* __restrict__ flag) {
    int total = *qcount;
    if (total > qmax) total = qmax;
    const int bytemode = *flag;
    int i = blockIdx.x * blockDim.x + threadIdx.x;
    int stride = gridDim.x * blockDim.x;
    for (; i < total; i += stride) {
        int2 c = qbuf[i];
        process_edge(c.y, c.x, w, src, rmb, input_idx, state, inp, acc, bytemode);
    }
}

// ---------------------------------------------------------------------------
// Kernel 4: activation + gather of the NOUT requested neurons.
// ---------------------------------------------------------------------------
__global__ void gather_out(const float* __restrict__ acc,
                           const int* __restrict__ act_id,
                           const int* __restrict__ out_ids,
                           float* __restrict__ out, int nout) {
    int i = blockIdx.x * blockDim.x + threadIdx.x;
    if (i >= nout) return;
    int n = out_ids[i];
    float x = acc[n];
    float y;
    switch (act_id[n]) {
        case 0: y = x; break;                                   // identity
        case 1: y = fmaxf(x, 0.0f); break;                      // relu
        case 2: y = x > 0.0f ? x : 0.01f * x; break;            // leaky_relu
        case 3: y = fminf(fmaxf(x, 0.0f), 1.0f); break;         // clipped_relu
        case 4: y = tanhf(x); break;                            // tanh
        case 5: y = 1.0f / (1.0f + expf(-x)); break;            // sigmoid
        case 6: y = fmaxf(x, 0.0f) + log1pf(expf(-fabsf(x))); break; // softplus
        default: y = fabsf(x); break;                           // abs
    }
    out[i] = y;
}

extern "C" void kernel_launch(void* const* d_in, const int* in_sizes, int n_in,
                              void* d_out, int out_size, void* d_ws, size_t ws_size,
                              hipStream_t stream) {
    const float* state     = (const float*)d_in[0];
    const float* weights   = (const float*)d_in[1];
    const float* biases    = (const float*)d_in[2];
    const float* inp       = (const float*)d_in[3];
    const int*   src       = (const int*)d_in[4];
    const int*   dst       = (const int*)d_in[5];
    const void*  rec_mask  = d_in[6];
    const int*   input_idx = (const int*)d_in[7];
    const int*   act_id    = (const int*)d_in[8];
    const int*   out_ids   = (const int*)d_in[9];
    float*       out       = (float*)d_out;

    const int N = in_sizes[0];
    const int E = in_sizes[1];
    const int NOUT = out_size;

    int*   flag   = (int*)d_ws;
    int*   qcount = (int*)((char*)d_ws + 4);
    float* acc    = (float*)((char*)d_ws + WS_ACC_OFF);

    size_t qoff = (size_t)WS_ACC_OFF + (size_t)N * 4;
    qoff = (qoff + 255) & ~(size_t)255;
    int2* qbuf = (int2*)((char*)d_ws + qoff);
    long long avail = (long long)ws_size - (long long)qoff;
    int qmax = 0;
    if (avail > 0) {
        long long q = avail / 8;
        qmax = (int)(q < (long long)QMAX_DEFAULT ? q : (long long)QMAX_DEFAULT);
    }

    // coarse shift: ceil(N >> shift) must fit FILT_WORDS*32 bits
    int shift = 0;
    while ((((long long)N + ((1LL << shift) - 1)) >> shift) > (long long)FILT_WORDS * 32)
        shift++;

    // 1) setup: detect rec_mask mode, zero qcount, init acc at out positions
    int nwords = E / 4;
    if (nwords > 2048) nwords = 2048;
    if (nwords < 1) nwords = 1;
    int setupBlocks = 1 + (NOUT + 255) / 256;
    setup<<<setupBlocks, 256, 0, stream>>>((const unsigned int*)rec_mask, nwords,
                                           flag, qcount, out_ids, state, biases,
                                           acc, NOUT);

    // 2) phase A: stream dst, compact candidate (e,d) pairs
    edge_compact<<<1024, 256, 0, stream>>>(
        dst, out_ids, NOUT, E, shift, qbuf, qcount, qmax,
        weights, src, (const unsigned char*)rec_mask, input_idx,
        state, inp, acc, flag);

    // 3) phase B: process candidates
    process_candidates<<<2048, 256, 0, stream>>>(
        qbuf, qcount, qmax,
        weights, src, (const unsigned char*)rec_mask, input_idx,
        state, inp, acc, flag);

    // 4) activation + gather
    gather_out<<<(NOUT + 255) / 256, 256, 0, stream>>>(acc, act_id, out_ids, out, NOUT);
}

// Round 6
// 67.465 us; speedup vs baseline: 1.4512x; 1.4512x over previous
//
#include <hip/hip_runtime.h>
#include <math.h>

#define REFRACTORY 0.33f
#define FILT_WORDS 8192      // 32 KB LDS coarse filter: 262144 bits
#define QCAP 1000            // per-block LDS queue entries (8 KB as int2)
#define QMAX_DEFAULT (4*1024*1024)

// ws layout:
//   [0,4)    flag (rec_mask byte-mode)
//   [4,8)    qcount
//   [256, 256+128K)      bm (exact 1-bit-per-neuron bitmap)
//   [256+128K, +4*N)     acc
//   then qbuf (int2 candidate entries)
#define WS_BM_OFF  256
#define WS_ACC_OFF (256 + 131072)

// ---------------------------------------------------------------------------
// Kernel 1 (setup): zero bm + qcount; block 0 also detects rec_mask mode
// (int32: dwords 0/1; packed bool bytes: dword view gives values > 1).
// ---------------------------------------------------------------------------
__global__ void setup(const unsigned int* __restrict__ rm, int nwords,
                      int* __restrict__ flag, int* __restrict__ qcount,
                      unsigned int* __restrict__ bm, int bmWords) {
    int gid = blockIdx.x * blockDim.x + threadIdx.x;
    int stride = gridDim.x * blockDim.x;
    for (int i = gid; i < bmWords; i += stride) bm[i] = 0u;
    if (gid == 0) *qcount = 0;
    if (blockIdx.x == 0) {
        __shared__ int s;
        if (threadIdx.x == 0) s = 0;
        __syncthreads();
        int found = 0;
        for (int i = threadIdx.x; i < nwords; i += blockDim.x)
            if (rm[i] > 1u) found = 1;
        if (found) atomicOr(&s, 1);
        __syncthreads();
        if (threadIdx.x == 0) *flag = s;
    }
}

// ---------------------------------------------------------------------------
// Kernel 2: mark output neurons in exact bitmap + init their accumulators.
// ---------------------------------------------------------------------------
__global__ void mark_init(const int* __restrict__ out_ids,
                          const float* __restrict__ state,
                          const float* __restrict__ biases,
                          unsigned int* __restrict__ bm,
                          float* __restrict__ acc, int nout) {
    int i = blockIdx.x * blockDim.x + threadIdx.x;
    if (i >= nout) return;
    int n = out_ids[i];
    atomicOr(&bm[((unsigned)n) >> 5], 1u << (n & 31));
    acc[n] = REFRACTORY * state[n] + biases[n];
}

// ---------------------------------------------------------------------------
// Full edge processing.
// ---------------------------------------------------------------------------
__device__ __forceinline__ void process_edge(
    int d, int e,
    const float* __restrict__ w, const int* __restrict__ src,
    const unsigned char* __restrict__ rmb, const int* __restrict__ input_idx,
    const float* __restrict__ state, const float* __restrict__ inp,
    float* __restrict__ acc, int bytemode) {
    int m = bytemode ? (int)rmb[e] : ((const int*)rmb)[e];
    float v = m ? REFRACTORY * state[src[e]] : inp[input_idx[e]];
    unsafeAtomicAdd(&acc[d], w[e] * v);
}

// ---------------------------------------------------------------------------
// Kernel 3 (phase A): build LDS coarse filter from out_ids, stream dst,
// enqueue (e, d) candidate pairs into a block-local LDS queue, flush once.
// No scattered global loads in the streaming loop.
// ---------------------------------------------------------------------------
__global__ void __launch_bounds__(256, 4)
edge_compact(const int* __restrict__ dst,
             const int* __restrict__ out_ids, int nout,
             int E, int shift,
             int2* __restrict__ qbuf, int* __restrict__ qcount, int qmax,
             const float* __restrict__ w, const int* __restrict__ src,
             const unsigned char* __restrict__ rmb,
             const int* __restrict__ input_idx,
             const float* __restrict__ state, const float* __restrict__ inp,
             float* __restrict__ acc,
             const int* __restrict__ flag) {
    __shared__ unsigned int filt[FILT_WORDS];
    __shared__ int2 lq[QCAP];
    __shared__ int lcnt, lbase;
    // zero + build coarse filter from out_ids (L2-hot broadcast read)
    {
        uint4* f4 = (uint4*)filt;
        uint4 z = make_uint4(0, 0, 0, 0);
        for (int i = threadIdx.x; i < FILT_WORDS / 4; i += blockDim.x)
            f4[i] = z;
    }
    if (threadIdx.x == 0) lcnt = 0;
    __syncthreads();
    for (int i = threadIdx.x; i < nout; i += blockDim.x) {
        unsigned g = ((unsigned)out_ids[i]) >> shift;
        atomicOr(&filt[g >> 5], 1u << (g & 31));
    }
    __syncthreads();

    const int bytemode = *flag;
    const int sh5 = shift + 5;
    int gtid = blockIdx.x * blockDim.x + threadIdx.x;
    int gstride = gridDim.x * blockDim.x;
    int nq = E >> 2;
    const int4* d4p = (const int4*)dst;

#define SLOT(dv, ev, valid)                                                    \
    {                                                                          \
        unsigned dd = (unsigned)(dv);                                          \
        bool c = (valid) && ((filt[dd >> sh5] >> ((dd >> shift) & 31)) & 1u);  \
        if (c) {                                                               \
            int off = atomicAdd(&lcnt, 1);                                     \
            if (off < QCAP) lq[off] = make_int2((ev), (int)dd);                \
            else process_edge((int)dd, (ev), w, src, rmb, input_idx,           \
                              state, inp, acc, bytemode);                      \
        }                                                                      \
    }

    for (int t = gtid; t < nq; t += 2 * gstride) {
        int4 A = d4p[t];
        int t2 = t + gstride;
        bool has2 = (t2 < nq);
        int4 B = has2 ? d4p[t2] : make_int4(0, 0, 0, 0);
        int ea = t << 2;
        SLOT(A.x, ea + 0, true);
        SLOT(A.y, ea + 1, true);
        SLOT(A.z, ea + 2, true);
        SLOT(A.w, ea + 3, true);
        int eb = t2 << 2;
        SLOT(B.x, eb + 0, has2);
        SLOT(B.y, eb + 1, has2);
        SLOT(B.z, eb + 2, has2);
        SLOT(B.w, eb + 3, has2);
    }
#undef SLOT

    // tail edges (E not divisible by 4): process inline (correct regardless)
    int rem = E - nq * 4;
    if (gtid < rem) {
        int e = nq * 4 + gtid;
        int d = dst[e];
        process_edge(d, e, w, src, rmb, input_idx, state, inp, acc, bytemode);
    }

    // block flush
    __syncthreads();
    int n = lcnt < QCAP ? lcnt : QCAP;
    if (threadIdx.x == 0) lbase = atomicAdd(qcount, n);
    __syncthreads();
    int base = lbase;
    for (int i = threadIdx.x; i < n; i += blockDim.x) {
        int gi = base + i;
        if (gi < qmax) qbuf[gi] = lq[i];
        else {  // global queue overflow (rare/never): process inline
            int2 c = lq[i];
            process_edge(c.y, c.x, w, src, rmb, input_idx, state, inp, acc, bytemode);
        }
    }
}

// ---------------------------------------------------------------------------
// Kernel 4 (phase B): probe exact bitmap (L2-resident, 128 KB) FIRST, then
// full processing for true hits only (~27% of candidates).
// ---------------------------------------------------------------------------
__global__ void __launch_bounds__(256)
process_candidates(const int2* __restrict__ qbuf, const int* __restrict__ qcount,
                   int qmax,
                   const unsigned int* __restrict__ bm,
                   const float* __restrict__ w, const int* __restrict__ src,
                   const unsigned char* __restrict__ rmb,
                   const int* __restrict__ input_idx,
                   const float* __restrict__ state, const float* __restrict__ inp,
                   float* __restrict__ acc,
                   const int* __restrict__ flag) {
    int total = *qcount;
    if (total > qmax) total = qmax;
    const int bytemode = *flag;
    int i = blockIdx.x * blockDim.x + threadIdx.x;
    int stride = gridDim.x * blockDim.x;
    for (; i < total; i += stride) {
        int2 c = qbuf[i];
        unsigned d = (unsigned)c.y;
        if ((bm[d >> 5] >> (d & 31)) & 1u)
            process_edge(c.y, c.x, w, src, rmb, input_idx, state, inp, acc, bytemode);
    }
}

// ---------------------------------------------------------------------------
// Kernel 5: activation + gather of the NOUT requested neurons.
// ---------------------------------------------------------------------------
__global__ void gather_out(const float* __restrict__ acc,
                           const int* __restrict__ act_id,
                           const int* __restrict__ out_ids,
                           float* __restrict__ out, int nout) {
    int i = blockIdx.x * blockDim.x + threadIdx.x;
    if (i >= nout) return;
    int n = out_ids[i];
    float x = acc[n];
    float y;
    switch (act_id[n]) {
        case 0: y = x; break;                                   // identity
        case 1: y = fmaxf(x, 0.0f); break;                      // relu
        case 2: y = x > 0.0f ? x : 0.01f * x; break;            // leaky_relu
        case 3: y = fminf(fmaxf(x, 0.0f), 1.0f); break;         // clipped_relu
        case 4: y = tanhf(x); break;                            // tanh
        case 5: y = 1.0f / (1.0f + expf(-x)); break;            // sigmoid
        case 6: y = fmaxf(x, 0.0f) + log1pf(expf(-fabsf(x))); break; // softplus
        default: y = fabsf(x); break;                           // abs
    }
    out[i] = y;
}

extern "C" void kernel_launch(void* const* d_in, const int* in_sizes, int n_in,
                              void* d_out, int out_size, void* d_ws, size_t ws_size,
                              hipStream_t stream) {
    const float* state     = (const float*)d_in[0];
    const float* weights   = (const float*)d_in[1];
    const float* biases    = (const float*)d_in[2];
    const float* inp       = (const float*)d_in[3];
    const int*   src       = (const int*)d_in[4];
    const int*   dst       = (const int*)d_in[5];
    const void*  rec_mask  = d_in[6];
    const int*   input_idx = (const int*)d_in[7];
    const int*   act_id    = (const int*)d_in[8];
    const int*   out_ids   = (const int*)d_in[9];
    float*       out       = (float*)d_out;

    const int N = in_sizes[0];
    const int E = in_sizes[1];
    const int NOUT = out_size;

    int*          flag   = (int*)d_ws;
    int*          qcount = (int*)((char*)d_ws + 4);
    unsigned int* bm     = (unsigned int*)((char*)d_ws + WS_BM_OFF);
    float*        acc    = (float*)((char*)d_ws + WS_ACC_OFF);

    size_t qoff = (size_t)WS_ACC_OFF + (size_t)N * 4;
    qoff = (qoff + 255) & ~(size_t)255;
    int2* qbuf = (int2*)((char*)d_ws + qoff);
    long long avail = (long long)ws_size - (long long)qoff;
    int qmax = 0;
    if (avail > 0) {
        long long q = avail / 8;
        qmax = (int)(q < (long long)QMAX_DEFAULT ? q : (long long)QMAX_DEFAULT);
    }

    const int bmWords = (N + 31) / 32;

    // coarse shift: ceil(N >> shift) must fit FILT_WORDS*32 bits
    int shift = 0;
    while ((((long long)N + ((1LL << shift) - 1)) >> shift) > (long long)FILT_WORDS * 32)
        shift++;

    // 1) setup: zero bm + qcount, detect rec_mask mode
    int nwords = E / 4;
    if (nwords > 2048) nwords = 2048;
    if (nwords < 1) nwords = 1;
    setup<<<64, 256, 0, stream>>>((const unsigned int*)rec_mask, nwords,
                                  flag, qcount, bm, bmWords);

    // 2) mark output neurons + init their accumulators
    mark_init<<<(NOUT + 255) / 256, 256, 0, stream>>>(out_ids, state, biases,
                                                      bm, acc, NOUT);

    // 3) phase A: stream dst, compact candidate (e,d) pairs
    edge_compact<<<1024, 256, 0, stream>>>(
        dst, out_ids, NOUT, E, shift, qbuf, qcount, qmax,
        weights, src, (const unsigned char*)rec_mask, input_idx,
        state, inp, acc, flag);

    // 4) phase B: bm-probe then process true hits
    process_candidates<<<2048, 256, 0, stream>>>(
        qbuf, qcount, qmax, bm,
        weights, src, (const unsigned char*)rec_mask, input_idx,
        state, inp, acc, flag);

    // 5) activation + gather
    gather_out<<<(NOUT + 255) / 256, 256, 0, stream>>>(acc, act_id, out_ids, out, NOUT);
}

// Round 7
// 42.363 us; speedup vs baseline: 2.3110x; 1.5925x over previous
//
#include <hip/hip_runtime.h>
#include <math.h>

#define REFRACTORY 0.33f
#define FILT_WORDS 32768     // 128 KB LDS bitmap: 1,048,576 bits (exact for N<=2^20)
#define QCAP 2048            // per-block LDS queue entries (16 KB as int2)

// ws layout:
//   [0,4)    flag (rec_mask byte-mode)
//   [256, 256+4*N)  acc
#define WS_ACC_OFF 256

// ---------------------------------------------------------------------------
// Kernel 1 (setup): block 0 detects rec_mask storage mode (int32: dwords 0/1;
// packed bool bytes: dword view > 1); blocks 1.. init acc = 0.33*state + bias
// at output-neuron positions (the only acc slots ever read).
// ---------------------------------------------------------------------------
__global__ void setup(const unsigned int* __restrict__ rm, int nwords,
                      int* __restrict__ flag,
                      const int* __restrict__ out_ids,
                      const float* __restrict__ state,
                      const float* __restrict__ biases,
                      float* __restrict__ acc, int nout) {
    if (blockIdx.x == 0) {
        __shared__ int s;
        if (threadIdx.x == 0) s = 0;
        __syncthreads();
        int found = 0;
        for (int i = threadIdx.x; i < nwords; i += blockDim.x)
            if (rm[i] > 1u) found = 1;
        if (found) atomicOr(&s, 1);
        __syncthreads();
        if (threadIdx.x == 0) *flag = s;
    } else {
        int i = (blockIdx.x - 1) * blockDim.x + threadIdx.x;
        if (i < nout) {
            int n = out_ids[i];
            acc[n] = REFRACTORY * state[n] + biases[n];
        }
    }
}

// ---------------------------------------------------------------------------
// Full edge processing. Adds always land on the edge's TRUE dst, so even a
// coarse-filter false positive (only possible if N > 2^20) is harmless:
// acc is only read at out_ids positions.
// ---------------------------------------------------------------------------
__device__ __forceinline__ void process_edge(
    int d, int e,
    const float* __restrict__ w, const int* __restrict__ src,
    const unsigned char* __restrict__ rmb, const int* __restrict__ input_idx,
    const float* __restrict__ state, const float* __restrict__ inp,
    float* __restrict__ acc, int bytemode) {
    int m = bytemode ? (int)rmb[e] : ((const int*)rmb)[e];
    float v = m ? REFRACTORY * state[src[e]] : inp[input_idx[e]];
    unsafeAtomicAdd(&acc[d], w[e] * v);
}

// ---------------------------------------------------------------------------
// Kernel 2 (fused): build EXACT 128 KB LDS bitmap from out_ids, stream dst,
// enqueue hits (zero false positives) into LDS queue, process queue at block
// end with lane-independent chains. One block per CU.
// ---------------------------------------------------------------------------
__global__ void __launch_bounds__(1024, 1)
edge_fused(const int* __restrict__ dst,
           const int* __restrict__ out_ids, int nout,
           int E, int shift,
           const float* __restrict__ w, const int* __restrict__ src,
           const unsigned char* __restrict__ rmb,
           const int* __restrict__ input_idx,
           const float* __restrict__ state, const float* __restrict__ inp,
           float* __restrict__ acc,
           const int* __restrict__ flag) {
    __shared__ unsigned int filt[FILT_WORDS];
    __shared__ int2 lq[QCAP];
    __shared__ int lcnt;

    // zero bitmap
    {
        uint4* f4 = (uint4*)filt;
        uint4 z = make_uint4(0, 0, 0, 0);
        for (int i = threadIdx.x; i < FILT_WORDS / 4; i += blockDim.x)
            f4[i] = z;
    }
    if (threadIdx.x == 0) lcnt = 0;
    __syncthreads();
    // build exact membership bitmap from out_ids (L2-hot broadcast read)
    for (int i = threadIdx.x; i < nout; i += blockDim.x) {
        unsigned g = ((unsigned)out_ids[i]) >> shift;
        atomicOr(&filt[g >> 5], 1u << (g & 31));
    }
    __syncthreads();

    const int bytemode = *flag;
    const int sh5 = shift + 5;
    int gtid = blockIdx.x * blockDim.x + threadIdx.x;
    int gstride = gridDim.x * blockDim.x;
    int nq = E >> 2;
    const int4* d4p = (const int4*)dst;

#define SLOT(dv, ev, valid)                                                    \
    {                                                                          \
        unsigned dd = (unsigned)(dv);                                          \
        bool c = (valid) && ((filt[dd >> sh5] >> ((dd >> shift) & 31)) & 1u);  \
        if (c) {                                                               \
            int off = atomicAdd(&lcnt, 1);                                     \
            if (off < QCAP) lq[off] = make_int2((ev), (int)dd);                \
            else process_edge((int)dd, (ev), w, src, rmb, input_idx,           \
                              state, inp, acc, bytemode);                      \
        }                                                                      \
    }

    for (int t = gtid; t < nq; t += 2 * gstride) {
        int4 A = d4p[t];
        int t2 = t + gstride;
        bool has2 = (t2 < nq);
        int4 B = has2 ? d4p[t2] : make_int4(0, 0, 0, 0);
        int ea = t << 2;
        SLOT(A.x, ea + 0, true);
        SLOT(A.y, ea + 1, true);
        SLOT(A.z, ea + 2, true);
        SLOT(A.w, ea + 3, true);
        int eb = t2 << 2;
        SLOT(B.x, eb + 0, has2);
        SLOT(B.y, eb + 1, has2);
        SLOT(B.z, eb + 2, has2);
        SLOT(B.w, eb + 3, has2);
    }
#undef SLOT

    // tail edges (E not divisible by 4): process inline (true-dst adds)
    int rem = E - nq * 4;
    if (gtid < rem) {
        int e = nq * 4 + gtid;
        int d = dst[e];
        process_edge(d, e, w, src, rmb, input_idx, state, inp, acc, bytemode);
    }

    // process this block's queued hits; lane-independent scattered chains
    __syncthreads();
    int n = lcnt < QCAP ? lcnt : QCAP;
    for (int i = threadIdx.x; i < n; i += blockDim.x) {
        int2 c = lq[i];
        process_edge(c.y, c.x, w, src, rmb, input_idx, state, inp, acc, bytemode);
    }
}

// ---------------------------------------------------------------------------
// Kernel 3: activation + gather of the NOUT requested neurons.
// ---------------------------------------------------------------------------
__global__ void gather_out(const float* __restrict__ acc,
                           const int* __restrict__ act_id,
                           const int* __restrict__ out_ids,
                           float* __restrict__ out, int nout) {
    int i = blockIdx.x * blockDim.x + threadIdx.x;
    if (i >= nout) return;
    int n = out_ids[i];
    float x = acc[n];
    float y;
    switch (act_id[n]) {
        case 0: y = x; break;                                   // identity
        case 1: y = fmaxf(x, 0.0f); break;                      // relu
        case 2: y = x > 0.0f ? x : 0.01f * x; break;            // leaky_relu
        case 3: y = fminf(fmaxf(x, 0.0f), 1.0f); break;         // clipped_relu
        case 4: y = tanhf(x); break;                            // tanh
        case 5: y = 1.0f / (1.0f + expf(-x)); break;            // sigmoid
        case 6: y = fmaxf(x, 0.0f) + log1pf(expf(-fabsf(x))); break; // softplus
        default: y = fabsf(x); break;                           // abs
    }
    out[i] = y;
}

extern "C" void kernel_launch(void* const* d_in, const int* in_sizes, int n_in,
                              void* d_out, int out_size, void* d_ws, size_t ws_size,
                              hipStream_t stream) {
    const float* state     = (const float*)d_in[0];
    const float* weights   = (const float*)d_in[1];
    const float* biases    = (const float*)d_in[2];
    const float* inp       = (const float*)d_in[3];
    const int*   src       = (const int*)d_in[4];
    const int*   dst       = (const int*)d_in[5];
    const void*  rec_mask  = d_in[6];
    const int*   input_idx = (const int*)d_in[7];
    const int*   act_id    = (const int*)d_in[8];
    const int*   out_ids   = (const int*)d_in[9];
    float*       out       = (float*)d_out;

    const int N = in_sizes[0];
    const int E = in_sizes[1];
    const int NOUT = out_size;

    int*   flag = (int*)d_ws;
    float* acc  = (float*)((char*)d_ws + WS_ACC_OFF);

    // filter granularity: shift=0 (exact) when N fits 2^20 bits
    int shift = 0;
    while ((((long long)N + ((1LL << shift) - 1)) >> shift) > (long long)FILT_WORDS * 32)
        shift++;

    // 1) setup: detect rec_mask mode + init acc at out positions
    int nwords = E / 4;
    if (nwords > 2048) nwords = 2048;
    if (nwords < 1) nwords = 1;
    int setupBlocks = 1 + (NOUT + 255) / 256;
    setup<<<setupBlocks, 256, 0, stream>>>((const unsigned int*)rec_mask, nwords,
                                           flag, out_ids, state, biases, acc, NOUT);

    // 2) fused: filter + stream + enqueue + process (one block per CU)
    edge_fused<<<256, 1024, 0, stream>>>(
        dst, out_ids, NOUT, E, shift,
        weights, src, (const unsigned char*)rec_mask, input_idx,
        state, inp, acc, flag);

    // 3) activation + gather
    gather_out<<<(NOUT + 255) / 256, 256, 0, stream>>>(acc, act_id, out_ids, out, NOUT);
}